// Round 14
// baseline (48.544 us; speedup 1.0000x reference)
//
#include <hip/hip_runtime.h>
#include <hip/hip_bf16.h>
#include <stdint.h>

// Problem constants
#define B_ROWS 16384
#define F_DIM  512
#define K_OUT  1000
#define K_PAD  1024

// GEMM tile (128x128, BK=64, 4 waves, 66KB LDS -> 2 blocks/CU resident)
#define BM 128
#define BN 128
#define BK 64

typedef __attribute__((ext_vector_type(4))) float f32x4;
typedef __attribute__((ext_vector_type(8))) short short8;
typedef unsigned short u16;
typedef unsigned int   u32;

// Workspace layout (bytes)
#define OFF_DB   0                               // 16384*512*2 = 16777216
#define OFF_WB   16777216                        // 1024*512*2  = 1048576
#define OFF_DSQ  (16777216 + 1048576)            // 16384*4     = 65536
#define OFF_WSQ  (16777216 + 1048576 + 65536)    // 1024*4      = 4096

// LDS: 2 staging buffers of (A 16KB + B 16KB) = 64KB (R7 layout);
// epilogue overlays two [64][132] f32 chunk buffers: ch0 @0, ch1 @33792.
#define LDS_SZ 67584

__device__ __forceinline__ u16 f2bf(float f) {
  union { float f; u32 u; } v; v.f = f;
  u32 u = v.u;
  u32 r = (u + 0x7fffu + ((u >> 16) & 1u)) >> 16;   // RNE
  return (u16)r;
}

// ---- merged prep: cast D,W -> bf16 (+pad W), row sums of squares ----
__global__ void prep(const float* __restrict__ D, const float* __restrict__ W,
                     u16* __restrict__ Db, u16* __restrict__ Wb,
                     float* __restrict__ dsq, float* __restrict__ wsq) {
  int w    = threadIdx.x >> 6;
  int lane = threadIdx.x & 63;
  if (blockIdx.x < B_ROWS / 4) {
    int row = blockIdx.x * 4 + w;
    const float* src = D + (size_t)row * F_DIM + lane * 8;
    float4 v0 = *(const float4*)src;
    float4 v1 = *(const float4*)(src + 4);
    float s = v0.x*v0.x + v0.y*v0.y + v0.z*v0.z + v0.w*v0.w
            + v1.x*v1.x + v1.y*v1.y + v1.z*v1.z + v1.w*v1.w;
#pragma unroll
    for (int off = 32; off >= 1; off >>= 1) s += __shfl_xor(s, off);
    if (lane == 0) dsq[row] = s;
    uint4 p;
    p.x = (u32)f2bf(v0.x) | ((u32)f2bf(v0.y) << 16);
    p.y = (u32)f2bf(v0.z) | ((u32)f2bf(v0.w) << 16);
    p.z = (u32)f2bf(v1.x) | ((u32)f2bf(v1.y) << 16);
    p.w = (u32)f2bf(v1.z) | ((u32)f2bf(v1.w) << 16);
    *(uint4*)(Db + (size_t)row * F_DIM + lane * 8) = p;
  } else {
    int row = (blockIdx.x - B_ROWS / 4) * 4 + w;
    uint4 p; p.x = p.y = p.z = p.w = 0u;
    float s = 0.f;
    if (row < K_OUT) {
      const float* src = W + (size_t)row * F_DIM + lane * 8;
      float4 v0 = *(const float4*)src;
      float4 v1 = *(const float4*)(src + 4);
      s = v0.x*v0.x + v0.y*v0.y + v0.z*v0.z + v0.w*v0.w
        + v1.x*v1.x + v1.y*v1.y + v1.z*v1.z + v1.w*v1.w;
      p.x = (u32)f2bf(v0.x) | ((u32)f2bf(v0.y) << 16);
      p.y = (u32)f2bf(v0.z) | ((u32)f2bf(v0.w) << 16);
      p.z = (u32)f2bf(v1.x) | ((u32)f2bf(v1.y) << 16);
      p.w = (u32)f2bf(v1.z) | ((u32)f2bf(v1.w) << 16);
    }
#pragma unroll
    for (int off = 32; off >= 1; off >>= 1) s += __shfl_xor(s, off);
    if (lane == 0) wsq[row] = s;
    *(uint4*)(Wb + (size_t)row * F_DIM + lane * 8) = p;
  }
}

// ---- async global -> LDS, 16B per lane (dest is wave-uniform base + lane*16) ----
__device__ __forceinline__ void gload_lds16(const void* g, void* l) {
  __builtin_amdgcn_global_load_lds(
      (const __attribute__((address_space(1))) void*)g,
      (__attribute__((address_space(3))) void*)l,
      16, 0, 0);
}

// ---- main GEMM + fused epilogue: R7 K-loop + pipelined NT-store epilogue ----
// out[m][n] = gamma[n] * (2*cross[m][n] - dsq[m] - wsq[n]), n < K_OUT
//
// Staging tile [128 rows][64 k] bf16 (16KB each A,B; double-buffered = 64KB).
// Row = 128B = 8 slots of 16B; k-slot s of row r stored at (s ^ (r&7)) via
// pre-swizzled global source (rule #21). Frag reads use the same XOR.
//
// Per K-tile (2 barriers, counted vmcnt(8), no vmcnt(0) in loop):
//   issue 8 gload_lds for tile t+1 into buf[(t+1)&1]   (phantom wrap at t=7)
//   s_waitcnt vmcnt(8)  -> exactly tile t's 8 loads have landed; s_barrier
//   16 ds_read_b128 frags; setprio(1); 32 MFMA; setprio(0); s_barrier

#define STAGE_A(h)                                                             \
  _Pragma("unroll") for (int j = 0; j < 2; ++j) {                              \
    int rb = (h) * 32 + j * 64 + w * 8;                                        \
    int r  = rb + (lane >> 3);                                                 \
    int sc = s8 ^ (r & 7);                                                     \
    gload_lds16(Ag + (size_t)r * F_DIM + kbn + sc * 8, sAn + rb * 128);        \
  }

#define STAGE_B(q)                                                             \
  _Pragma("unroll") for (int j = 0; j < 2; ++j) {                              \
    int rb = (q) * 32 + j * 64 + w * 8;                                        \
    int r  = rb + (lane >> 3);                                                 \
    int sc = s8 ^ (r & 7);                                                     \
    gload_lds16(Bg + (size_t)r * F_DIM + kbn + sc * 8, sBn + rb * 128);        \
  }

// write one 64-row output chunk (c = 0 or 1) into LDS chunk buffer chp
#define CHUNK_WRITE(c, chp)                                                    \
  _Pragma("unroll") for (int mi = 0; mi < 4; ++mi) {                           \
    const int row_l = mi * 16 + lk4 * 4;                                       \
    _Pragma("unroll") for (int j = 0; j < 4; ++j) {                            \
      float dq = (j == 0) ? dl[mi].x : (j == 1) ? dl[mi].y                     \
               : (j == 2) ? dl[mi].z : dl[mi].w;                               \
      _Pragma("unroll") for (int ni = 0; ni < 4; ++ni) {                       \
        (chp)[(row_l + j) * 132 + wn * 64 + ni * 16 + lr] =                    \
            g_[ni] * (2.f * acc[mi][ni][j] - dq - wq_[ni]);                    \
      }                                                                        \
    }                                                                          \
  }

// store one 64-row chunk from LDS to out (nontemporal: write-once data)
#define CHUNK_STORE(c, chp)                                                    \
  _Pragma("unroll") for (int half = 0; half < 2; ++half) {                     \
    _Pragma("unroll") for (int s = 0; s < 4; ++s) {                            \
      int row = half * 32 + rl;                                                \
      int col = cb + s * 32;                                                   \
      if (n0 + col < K_OUT) {                                                  \
        f32x4 v = *(const f32x4*)&(chp)[row * 132 + col];                      \
        __builtin_nontemporal_store(                                           \
            v, (f32x4*)&out[(size_t)(m0 + (c) * 64 + row) * K_OUT + n0 + col]); \
      }                                                                        \
    }                                                                          \
  }

__global__ __launch_bounds__(256, 2) void gemm_eps(
    const u16* __restrict__ A,   // [B_ROWS][F_DIM] bf16
    const u16* __restrict__ Bw,  // [K_PAD][F_DIM]  bf16 (padded rows are 0)
    const float* __restrict__ dsq,
    const float* __restrict__ wsq,
    const float* __restrict__ gamma,
    float* __restrict__ out) {
  __shared__ __align__(16) char lds[LDS_SZ];

  const int tid  = threadIdx.x;
  const int w    = tid >> 6;     // wave 0..3
  const int lane = tid & 63;
  const int lr   = lane & 15;
  const int lk4  = lane >> 4;
  const int wm   = w >> 1;       // 2 M-waves
  const int wn   = w & 1;        // 2 N-waves

  // XCD-aware swizzle (grid=1024, %8==0 -> bijective). Consecutive wg on one
  // XCD share the A-panel (same mt) -> A re-reads are local-L2 hits.
  const int bid = blockIdx.x;
  const int wg  = (bid & 7) * 128 + (bid >> 3);
  const int mt  = wg >> 3;       // 128 M-tiles
  const int nt  = wg & 7;        // 8 N-tiles
  const int m0  = mt * BM;
  const int n0  = nt * BN;

  const u16* Ag = A  + (size_t)m0 * F_DIM;
  const u16* Bg = Bw + (size_t)n0 * F_DIM;

  const int s8 = lane & 7;       // staging 16B slot

  f32x4 acc[4][4];
#pragma unroll
  for (int i = 0; i < 4; ++i)
#pragma unroll
    for (int j = 0; j < 4; ++j) acc[i][j] = (f32x4){0.f, 0.f, 0.f, 0.f};

  // epilogue operands prefetched (latency hides under the K-loop)
  float g_[4], wq_[4];
  float4 dl[4];
#pragma unroll
  for (int ni = 0; ni < 4; ++ni) {
    int col = n0 + wn * 64 + ni * 16 + lr;
    g_[ni]  = (col < K_OUT) ? gamma[col] : 0.f;
    wq_[ni] = wsq[col & (K_PAD - 1)];
  }
#pragma unroll
  for (int mi = 0; mi < 4; ++mi)
    dl[mi] = *(const float4*)&dsq[m0 + wm * 64 + mi * 16 + lk4 * 4];

  // prologue: stage K-tile 0 into buf0 (8 loads/thread, left in flight)
  {
    char* sAn = lds;
    char* sBn = lds + 16384;
    const int kbn = 0;
    STAGE_A(0) STAGE_A(1) STAGE_B(0) STAGE_B(1)
  }

#pragma unroll 2
  for (int t = 0; t < 8; ++t) {
    const char* sAc = lds + (t & 1) * 32768;
    const char* sBc = sAc + 16384;
    char* sAn = lds + ((t + 1) & 1) * 32768;
    char* sBn = sAn + 16384;
    const int kbn = ((t + 1) & 7) * BK;   // t=7 phantom wraps to k=0: harmless

    // issue next tile's 8 loads (kept in flight across this tile's compute)
    STAGE_A(0) STAGE_A(1) STAGE_B(0) STAGE_B(1)

    asm volatile("s_waitcnt vmcnt(8)" ::: "memory");  // tile t resident
    __builtin_amdgcn_s_barrier();
    asm volatile("" ::: "memory");

    short8 a[2][4], b[2][4];
#pragma unroll
    for (int kk = 0; kk < 2; ++kk)
#pragma unroll
      for (int mi = 0; mi < 4; ++mi) {
        int rA = wm * 64 + mi * 16 + lr;
        a[kk][mi] = *(const short8*)(sAc + rA * 128 +
                                     ((((kk << 2) + lk4) ^ (rA & 7)) << 4));
        int rB = wn * 64 + mi * 16 + lr;
        b[kk][mi] = *(const short8*)(sBc + rB * 128 +
                                     ((((kk << 2) + lk4) ^ (rB & 7)) << 4));
      }

    __builtin_amdgcn_s_setprio(1);
#pragma unroll
    for (int kk = 0; kk < 2; ++kk)
#pragma unroll
      for (int mi = 0; mi < 4; ++mi)
#pragma unroll
        for (int ni = 0; ni < 4; ++ni)
          acc[mi][ni] = __builtin_amdgcn_mfma_f32_16x16x32_bf16(
              a[kk][mi], b[kk][ni], acc[mi][ni], 0, 0, 0);
    __builtin_amdgcn_s_setprio(0);

    asm volatile("" ::: "memory");
    __builtin_amdgcn_s_barrier();   // buf[t&1] reads done before t+1 overwrites
  }

  // ---- pipelined epilogue: chunk-1 LDS writes overlap chunk-0 HBM stores ----
  // First __syncthreads drains vmcnt(0)+lgkmcnt(0): phantom tile-8 stages land
  // in buf0 before we overwrite LDS with the chunk buffers.
  float* ch0 = (float*)lds;            // [64][132] f32 @ [0, 33792)
  float* ch1 = (float*)(lds + 33792);  // [64][132] f32 @ [33792, 67584)
  const int rl = tid >> 3;
  const int cb = (tid & 7) << 2;

  __syncthreads();   // K-loop LDS quiesced; phantom gloads drained
  if (wm == 0) { CHUNK_WRITE(0, ch0) }
  __syncthreads();   // ch0 visible to all waves
  if (wm == 1) { CHUNK_WRITE(1, ch1) }   // overlaps ch0's stores below
  CHUNK_STORE(0, ch0)
  __syncthreads();   // ch1 visible (ch0 stores already issued)
  CHUNK_STORE(1, ch1)
}

extern "C" void kernel_launch(void* const* d_in, const int* in_sizes, int n_in,
                              void* d_out, int out_size, void* d_ws, size_t ws_size,
                              hipStream_t stream) {
  const float* D     = (const float*)d_in[0];
  const float* W     = (const float*)d_in[1];
  const float* gamma = (const float*)d_in[2];
  float* out = (float*)d_out;
  char*  ws  = (char*)d_ws;

  u16*   Db  = (u16*)(ws + OFF_DB);
  u16*   Wb  = (u16*)(ws + OFF_WB);
  float* dsq = (float*)(ws + OFF_DSQ);
  float* wsq = (float*)(ws + OFF_WSQ);

  prep<<<B_ROWS / 4 + K_PAD / 4, 256, 0, stream>>>(D, W, Db, Wb, dsq, wsq);

  // grid = (16384/128) * (1024/128) = 1024 blocks, 2 resident/CU
  gemm_eps<<<(B_ROWS / BM) * (K_PAD / BN), 256, 0, stream>>>(
      Db, Wb, dsq, wsq, gamma, out);
}

// Round 15
// 39.715 us; speedup vs baseline: 1.2223x; 1.2223x over previous
//
#include <hip/hip_runtime.h>
#include <hip/hip_bf16.h>
#include <stdint.h>

// Problem constants
#define B_ROWS 16384
#define F_DIM  512
#define K_OUT  1000
#define K_PAD  1024

// GEMM tile (128x128, BK=64, 4 waves, 66KB LDS -> 2 blocks/CU resident)
#define BM 128
#define BN 128
#define BK 64

typedef __attribute__((ext_vector_type(4))) float f32x4;
typedef __attribute__((ext_vector_type(8))) short short8;
typedef unsigned short u16;
typedef unsigned int   u32;

// Workspace layout (bytes)
#define OFF_DB   0                               // 16384*512*2 = 16777216
#define OFF_WB   16777216                        // 1024*512*2  = 1048576
#define OFF_DSQ  (16777216 + 1048576)            // 16384*4     = 65536
#define OFF_WSQ  (16777216 + 1048576 + 65536)    // 1024*4      = 4096

// LDS: 2 staging buffers of (A 16KB + B 16KB) = 64KB (R7 layout);
// epilogue overlays two [64][132] f32 chunk buffers: ch0 @0, ch1 @33792.
#define LDS_SZ 67584

__device__ __forceinline__ u16 f2bf(float f) {
  union { float f; u32 u; } v; v.f = f;
  u32 u = v.u;
  u32 r = (u + 0x7fffu + ((u >> 16) & 1u)) >> 16;   // RNE
  return (u16)r;
}

// ---- merged prep: cast D,W -> bf16 (+pad W), row sums of squares ----
__global__ void prep(const float* __restrict__ D, const float* __restrict__ W,
                     u16* __restrict__ Db, u16* __restrict__ Wb,
                     float* __restrict__ dsq, float* __restrict__ wsq) {
  int w    = threadIdx.x >> 6;
  int lane = threadIdx.x & 63;
  if (blockIdx.x < B_ROWS / 4) {
    int row = blockIdx.x * 4 + w;
    const float* src = D + (size_t)row * F_DIM + lane * 8;
    float4 v0 = *(const float4*)src;
    float4 v1 = *(const float4*)(src + 4);
    float s = v0.x*v0.x + v0.y*v0.y + v0.z*v0.z + v0.w*v0.w
            + v1.x*v1.x + v1.y*v1.y + v1.z*v1.z + v1.w*v1.w;
#pragma unroll
    for (int off = 32; off >= 1; off >>= 1) s += __shfl_xor(s, off);
    if (lane == 0) dsq[row] = s;
    uint4 p;
    p.x = (u32)f2bf(v0.x) | ((u32)f2bf(v0.y) << 16);
    p.y = (u32)f2bf(v0.z) | ((u32)f2bf(v0.w) << 16);
    p.z = (u32)f2bf(v1.x) | ((u32)f2bf(v1.y) << 16);
    p.w = (u32)f2bf(v1.z) | ((u32)f2bf(v1.w) << 16);
    *(uint4*)(Db + (size_t)row * F_DIM + lane * 8) = p;
  } else {
    int row = (blockIdx.x - B_ROWS / 4) * 4 + w;
    uint4 p; p.x = p.y = p.z = p.w = 0u;
    float s = 0.f;
    if (row < K_OUT) {
      const float* src = W + (size_t)row * F_DIM + lane * 8;
      float4 v0 = *(const float4*)src;
      float4 v1 = *(const float4*)(src + 4);
      s = v0.x*v0.x + v0.y*v0.y + v0.z*v0.z + v0.w*v0.w
        + v1.x*v1.x + v1.y*v1.y + v1.z*v1.z + v1.w*v1.w;
      p.x = (u32)f2bf(v0.x) | ((u32)f2bf(v0.y) << 16);
      p.y = (u32)f2bf(v0.z) | ((u32)f2bf(v0.w) << 16);
      p.z = (u32)f2bf(v1.x) | ((u32)f2bf(v1.y) << 16);
      p.w = (u32)f2bf(v1.z) | ((u32)f2bf(v1.w) << 16);
    }
#pragma unroll
    for (int off = 32; off >= 1; off >>= 1) s += __shfl_xor(s, off);
    if (lane == 0) wsq[row] = s;
    *(uint4*)(Wb + (size_t)row * F_DIM + lane * 8) = p;
  }
}

// ---- async global -> LDS, 16B per lane (dest is wave-uniform base + lane*16) ----
__device__ __forceinline__ void gload_lds16(const void* g, void* l) {
  __builtin_amdgcn_global_load_lds(
      (const __attribute__((address_space(1))) void*)g,
      (__attribute__((address_space(3))) void*)l,
      16, 0, 0);
}

// ---- main GEMM + fused epilogue: R7 K-loop + pipelined epilogue ----
// out[m][n] = gamma[n] * (2*cross[m][n] - dsq[m] - wsq[n]), n < K_OUT
//
// Staging tile [128 rows][64 k] bf16 (16KB each A,B; double-buffered = 64KB).
// Row = 128B = 8 slots of 16B; k-slot s of row r stored at (s ^ (r&7)) via
// pre-swizzled global source (rule #21). Frag reads use the same XOR.
//
// Per K-tile (2 barriers, counted vmcnt(8), no vmcnt(0) in loop):
//   issue 8 gload_lds for tile t+1 into buf[(t+1)&1]   (phantom wrap at t=7)
//   s_waitcnt vmcnt(8)  -> exactly tile t's 8 loads have landed; s_barrier
//   16 ds_read_b128 frags; setprio(1); 32 MFMA; setprio(0); s_barrier

#define STAGE_A(h)                                                             \
  _Pragma("unroll") for (int j = 0; j < 2; ++j) {                              \
    int rb = (h) * 32 + j * 64 + w * 8;                                        \
    int r  = rb + (lane >> 3);                                                 \
    int sc = s8 ^ (r & 7);                                                     \
    gload_lds16(Ag + (size_t)r * F_DIM + kbn + sc * 8, sAn + rb * 128);        \
  }

#define STAGE_B(q)                                                             \
  _Pragma("unroll") for (int j = 0; j < 2; ++j) {                              \
    int rb = (q) * 32 + j * 64 + w * 8;                                        \
    int r  = rb + (lane >> 3);                                                 \
    int sc = s8 ^ (r & 7);                                                     \
    gload_lds16(Bg + (size_t)r * F_DIM + kbn + sc * 8, sBn + rb * 128);        \
  }

// write one 64-row output chunk (c = 0 or 1) into LDS chunk buffer chp
#define CHUNK_WRITE(c, chp)                                                    \
  _Pragma("unroll") for (int mi = 0; mi < 4; ++mi) {                           \
    const int row_l = mi * 16 + lk4 * 4;                                       \
    _Pragma("unroll") for (int j = 0; j < 4; ++j) {                            \
      float dq = (j == 0) ? dl[mi].x : (j == 1) ? dl[mi].y                     \
               : (j == 2) ? dl[mi].z : dl[mi].w;                               \
      _Pragma("unroll") for (int ni = 0; ni < 4; ++ni) {                       \
        (chp)[(row_l + j) * 132 + wn * 64 + ni * 16 + lr] =                    \
            g_[ni] * (2.f * acc[mi][ni][j] - dq - wq_[ni]);                    \
      }                                                                        \
    }                                                                          \
  }

// store one 64-row chunk from LDS to out (plain stores: L2 merges the
// misaligned head/tail lines of the 4000B-stride rows -- NT stores cost
// +16MB HBM RMW, measured R14)
#define CHUNK_STORE(c, chp)                                                    \
  _Pragma("unroll") for (int half = 0; half < 2; ++half) {                     \
    _Pragma("unroll") for (int s = 0; s < 4; ++s) {                            \
      int row = half * 32 + rl;                                                \
      int col = cb + s * 32;                                                   \
      if (n0 + col < K_OUT) {                                                  \
        f32x4 v = *(const f32x4*)&(chp)[row * 132 + col];                      \
        *(f32x4*)&out[(size_t)(m0 + (c) * 64 + row) * K_OUT + n0 + col] = v;   \
      }                                                                        \
    }                                                                          \
  }

__global__ __launch_bounds__(256, 2) void gemm_eps(
    const u16* __restrict__ A,   // [B_ROWS][F_DIM] bf16
    const u16* __restrict__ Bw,  // [K_PAD][F_DIM]  bf16 (padded rows are 0)
    const float* __restrict__ dsq,
    const float* __restrict__ wsq,
    const float* __restrict__ gamma,
    float* __restrict__ out) {
  __shared__ __align__(16) char lds[LDS_SZ];

  const int tid  = threadIdx.x;
  const int w    = tid >> 6;     // wave 0..3
  const int lane = tid & 63;
  const int lr   = lane & 15;
  const int lk4  = lane >> 4;
  const int wm   = w >> 1;       // 2 M-waves
  const int wn   = w & 1;        // 2 N-waves

  // XCD-aware swizzle (grid=1024, %8==0 -> bijective). Consecutive wg on one
  // XCD share the A-panel (same mt) -> A re-reads are local-L2 hits.
  const int bid = blockIdx.x;
  const int wg  = (bid & 7) * 128 + (bid >> 3);
  const int mt  = wg >> 3;       // 128 M-tiles
  const int nt  = wg & 7;        // 8 N-tiles
  const int m0  = mt * BM;
  const int n0  = nt * BN;

  const u16* Ag = A  + (size_t)m0 * F_DIM;
  const u16* Bg = Bw + (size_t)n0 * F_DIM;

  const int s8 = lane & 7;       // staging 16B slot

  f32x4 acc[4][4];
#pragma unroll
  for (int i = 0; i < 4; ++i)
#pragma unroll
    for (int j = 0; j < 4; ++j) acc[i][j] = (f32x4){0.f, 0.f, 0.f, 0.f};

  // epilogue operands prefetched (latency hides under the K-loop)
  float g_[4], wq_[4];
  float4 dl[4];
#pragma unroll
  for (int ni = 0; ni < 4; ++ni) {
    int col = n0 + wn * 64 + ni * 16 + lr;
    g_[ni]  = (col < K_OUT) ? gamma[col] : 0.f;
    wq_[ni] = wsq[col & (K_PAD - 1)];
  }
#pragma unroll
  for (int mi = 0; mi < 4; ++mi)
    dl[mi] = *(const float4*)&dsq[m0 + wm * 64 + mi * 16 + lk4 * 4];

  // prologue: stage K-tile 0 into buf0 (8 loads/thread, left in flight)
  {
    char* sAn = lds;
    char* sBn = lds + 16384;
    const int kbn = 0;
    STAGE_A(0) STAGE_A(1) STAGE_B(0) STAGE_B(1)
  }

#pragma unroll 2
  for (int t = 0; t < 8; ++t) {
    const char* sAc = lds + (t & 1) * 32768;
    const char* sBc = sAc + 16384;
    char* sAn = lds + ((t + 1) & 1) * 32768;
    char* sBn = sAn + 16384;
    const int kbn = ((t + 1) & 7) * BK;   // t=7 phantom wraps to k=0: harmless

    // issue next tile's 8 loads (kept in flight across this tile's compute)
    STAGE_A(0) STAGE_A(1) STAGE_B(0) STAGE_B(1)

    asm volatile("s_waitcnt vmcnt(8)" ::: "memory");  // tile t resident
    __builtin_amdgcn_s_barrier();
    asm volatile("" ::: "memory");

    short8 a[2][4], b[2][4];
#pragma unroll
    for (int kk = 0; kk < 2; ++kk)
#pragma unroll
      for (int mi = 0; mi < 4; ++mi) {
        int rA = wm * 64 + mi * 16 + lr;
        a[kk][mi] = *(const short8*)(sAc + rA * 128 +
                                     ((((kk << 2) + lk4) ^ (rA & 7)) << 4));
        int rB = wn * 64 + mi * 16 + lr;
        b[kk][mi] = *(const short8*)(sBc + rB * 128 +
                                     ((((kk << 2) + lk4) ^ (rB & 7)) << 4));
      }

    __builtin_amdgcn_s_setprio(1);
#pragma unroll
    for (int kk = 0; kk < 2; ++kk)
#pragma unroll
      for (int mi = 0; mi < 4; ++mi)
#pragma unroll
        for (int ni = 0; ni < 4; ++ni)
          acc[mi][ni] = __builtin_amdgcn_mfma_f32_16x16x32_bf16(
              a[kk][mi], b[kk][ni], acc[mi][ni], 0, 0, 0);
    __builtin_amdgcn_s_setprio(0);

    asm volatile("" ::: "memory");
    __builtin_amdgcn_s_barrier();   // buf[t&1] reads done before t+1 overwrites
  }

  // ---- pipelined epilogue: chunk-1 LDS writes overlap chunk-0 HBM stores ----
  // First __syncthreads drains vmcnt(0)+lgkmcnt(0): phantom tile-8 stages land
  // in buf0 before we overwrite LDS with the chunk buffers.
  float* ch0 = (float*)lds;            // [64][132] f32 @ [0, 33792)
  float* ch1 = (float*)(lds + 33792);  // [64][132] f32 @ [33792, 67584)
  const int rl = tid >> 3;
  const int cb = (tid & 7) << 2;

  __syncthreads();   // K-loop LDS quiesced; phantom gloads drained
  if (wm == 0) { CHUNK_WRITE(0, ch0) }
  __syncthreads();   // ch0 visible to all waves
  if (wm == 1) { CHUNK_WRITE(1, ch1) }   // overlaps ch0's stores below
  CHUNK_STORE(0, ch0)
  __syncthreads();   // ch1 visible (ch0 stores already issued)
  CHUNK_STORE(1, ch1)
}

extern "C" void kernel_launch(void* const* d_in, const int* in_sizes, int n_in,
                              void* d_out, int out_size, void* d_ws, size_t ws_size,
                              hipStream_t stream) {
  const float* D     = (const float*)d_in[0];
  const float* W     = (const float*)d_in[1];
  const float* gamma = (const float*)d_in[2];
  float* out = (float*)d_out;
  char*  ws  = (char*)d_ws;

  u16*   Db  = (u16*)(ws + OFF_DB);
  u16*   Wb  = (u16*)(ws + OFF_WB);
  float* dsq = (float*)(ws + OFF_DSQ);
  float* wsq = (float*)(ws + OFF_WSQ);

  prep<<<B_ROWS / 4 + K_PAD / 4, 256, 0, stream>>>(D, W, Db, Wb, dsq, wsq);

  // grid = (16384/128) * (1024/128) = 1024 blocks, 2 resident/CU
  gemm_eps<<<(B_ROWS / BM) * (K_PAD / BN), 256, 0, stream>>>(
      Db, Wb, dsq, wsq, gamma, out);
}